// Round 15
// baseline (3039.349 us; speedup 1.0000x reference)
//
#include <hip/hip_runtime.h>
#include <stdint.h>

#define N 4096
#define D 1024
#define TILE 512           // compacted rows per tile (8 tiles cover worst case)
#define THRF 0.25f
#define GBK 32             // K-step per LDS stage (k-major layout)
#define AG 6               // A granule stride (doubles): 4 used + 2 pad = 48 B
                           // -> 16B-aligned b128 reads, 2-way banks (free)
#define ASTR (16 * AG)     // 96 doubles per kk row of A
#define BSTR 34            // B LDS row stride in doubles (32 cols + 2 pad)
#define LSTR 4224          // u16 entries per row list slot (4096 + 128 sentinel pad)

// ---- All scratch lives in d_in[0] (16 MB; harness restores it before every
// timed launch; we copy E to d_out first on-stream). d_ws is never used.
// Numerics invariant (R6..R13-proven): sims = fp32( fp64_fma_chain(d=0..1023)/1024 ),
// ALL comparisons in fp32, (val desc, idx asc) ordering — matches np exactly.
// R29 structure (R28 + CONFLICT-FREE A-GRANULES): exact per-row candidate
// lists in COMPACTED space (k_prep stable-compacts alive -> idx[0..nA) and
// folds apply; k_gemm 64x32 fp64 k-major blocks; k_sort ballot-compacts
// candidates {cc>cr, v>=thr, !mgC-at-tile-start}, bitonic sorts keys
// ((~v_bits)<<32)|cc == (val desc, idx asc)). k_wgemm runs walk(t) on block 0
// CONCURRENTLY with gemm(t+1) on blocks 1.. (R26-proven; disjoint buffers).
// Walk = R24-proven paired resolve + R27-proven named-register prefetch
// (bit-identical to sequential walk; see R28 header). NEW: gemm's A tile is
// stored as 48-byte granules (As[kk][(r>>2)*AG + (r&3)]): R28 PMC showed
// SQ_LDS_BANK_CONFLICT=1.78e7/dispatch — the old As[kk][r] layout put the
// 16 b128 A-fragment reads on start banks (tr*8)%32 = 4-way conflict, and
// staging writes 4-way too; DS pipe (not fp64 FMA) was the gemm wall
// (VALUBusy 36.8%). With AG=6: reads start at banks (tr*12)%32 (2-way =
// free), stay 16B-aligned; staging writes land on distinct banks per wave.
// The per-output fp64 fma chain order is UNCHANGED (k0 outer 0,32..992; kk
// inner 0..31 => k=0..1023 sequential) -> sims bit-identical; only the LDS
// address mapping changed. Exactness of the merge resolution unchanged:
// lists are supersets of candidates available at the row's turn; first
// available in sorted order == argmax; exhausted list proves no cand >= thr.

__global__ void k_init(uint8_t* alive, uint8_t* consumedO, int* mcnt, int* acnt) {
    int x = blockIdx.x * blockDim.x + threadIdx.x;
    if (x < N) { alive[x] = 1; consumedO[x] = 0; }
    if (x < 8) { mcnt[x] = 0; acnt[x] = (x == 0) ? N : 0; }
}

// Round-start: fold previous round's consumption into alive, re-zero
// consumedO, stable-compact alive -> idx[0..nA), zero mgC, partner=-1,
// record acnt[round] = round-start alive count.
__global__ __launch_bounds__(1024) void k_prep(uint8_t* __restrict__ alive,
                                               uint8_t* __restrict__ consumedO,
                                               int* __restrict__ idx, int* __restrict__ nAp,
                                               uint8_t* __restrict__ mgC,
                                               int* __restrict__ partner,
                                               int* __restrict__ acnt, int rnd) {
    __shared__ int wsum[16];
    __shared__ int woff[16];
    int t = threadIdx.x, lane = t & 63, wv = t >> 6;
    int b4 = t * 4;
    uint32_t a4 = *(const uint32_t*)(alive + b4);        // bytes 0/1
    uint32_t c4 = *(const uint32_t*)(consumedO + b4);    // bytes 0/1
    a4 &= (c4 ^ 0x01010101u);                            // alive &= !consumed
    *(uint32_t*)(alive + b4) = a4;
    *(uint32_t*)(consumedO + b4) = 0u;
    int c0 = a4 & 1, c1 = (a4 >> 8) & 1, c2 = (a4 >> 16) & 1, c3 = (a4 >> 24) & 1;
    int c = c0 + c1 + c2 + c3;
    int pref = c;                                        // inclusive wave scan
    for (int off = 1; off < 64; off <<= 1) {
        int v = __shfl_up(pref, off);
        if (lane >= off) pref += v;
    }
    if (lane == 63) wsum[wv] = pref;
    __syncthreads();
    if (t == 0) {
        int s = 0;
        for (int w = 0; w < 16; ++w) { woff[w] = s; s += wsum[w]; }
        nAp[0] = s; acnt[rnd] = s;
    }
    __syncthreads();
    int pos = woff[wv] + pref - c;                       // exclusive position
    if (c0) idx[pos++] = b4;
    if (c1) idx[pos++] = b4 + 1;
    if (c2) idx[pos++] = b4 + 2;
    if (c3) idx[pos++] = b4 + 3;
    partner[b4] = -1; partner[b4 + 1] = -1; partner[b4 + 2] = -1; partner[b4 + 3] = -1;
    *(uint32_t*)(mgC + b4) = 0u;
}

// Shared gemm block body (64 rows x 32 cols, k-major double staging with
// 48B A-granules; fp64 fma chain order UNCHANGED — numerics-critical).
__device__ __forceinline__ void gemm_body(const float* __restrict__ E,
                                          const int* __restrict__ idx, int nA,
                                          float* __restrict__ simT,
                                          int t0, int bi, int cj,
                                          double As[GBK][ASTR], double Bs[GBK][BSTR],
                                          int* ra, int* ca) {
    int row0 = t0 + bi * 64;
    int col0 = cj * 32;
    if (row0 >= nA || col0 >= nA) return;
    if (col0 + 31 <= row0) return;  // wholly at/below diagonal: never read
    int t = threadIdx.x;
    if (t < 64) ra[t] = (row0 + t < nA) ? idx[row0 + t] : -1;
    else if (t < 96) { int u = t - 64; ca[u] = (col0 + u < nA) ? idx[col0 + u] : -1; }
    __syncthreads();
    int tr = t >> 4, tc = t & 15;            // rows tr*4+u (tr 0..15), cols 2tc+v
    int sr = t >> 3;                         // stage index 0..31
    int sq = t & 7;                          // k-quad 0..7 (4 floats each)
    double acc[4][2] = {};
    for (int k0 = 0; k0 < D; k0 += GBK) {
        for (int p = 0; p < 2; ++p) {        // A: 64 rows in 2 passes
            int r = sr + p * 32;
            int rid = ra[r];
            float4 av = make_float4(0.f, 0.f, 0.f, 0.f);
            if (rid >= 0) av = *(const float4*)(E + (size_t)rid * D + k0 + sq * 4);
            int gcol = (r >> 2) * AG + (r & 3);  // granule layout: bank-clean writes
            As[sq * 4 + 0][gcol] = (double)av.x; // f32->f64 exact (no rounding)
            As[sq * 4 + 1][gcol] = (double)av.y;
            As[sq * 4 + 2][gcol] = (double)av.z;
            As[sq * 4 + 3][gcol] = (double)av.w;
        }
        {                                    // B: 32 cols in 1 pass
            int cid = ca[sr];
            float4 bv = make_float4(0.f, 0.f, 0.f, 0.f);
            if (cid >= 0) bv = *(const float4*)(E + (size_t)cid * D + k0 + sq * 4);
            Bs[sq * 4 + 0][sr] = (double)bv.x;
            Bs[sq * 4 + 1][sr] = (double)bv.y;
            Bs[sq * 4 + 2][sr] = (double)bv.z;
            Bs[sq * 4 + 3][sr] = (double)bv.w;
        }
        __syncthreads();
        for (int kk = 0; kk < GBK; ++kk) {
            double2 a01 = *(const double2*)&As[kk][tr * AG];     // b128, 2-way=free
            double2 a23 = *(const double2*)&As[kk][tr * AG + 2];
            double2 b01 = *(const double2*)&Bs[kk][tc * 2];      // b128, broadcast
            double a[4] = {a01.x, a01.y, a23.x, a23.y};
            for (int u = 0; u < 4; ++u) {
                acc[u][0] = fma(a[u], b01.x, acc[u][0]);
                acc[u][1] = fma(a[u], b01.y, acc[u][1]);
            }
        }
        __syncthreads();
    }
    int rbase = bi * 64 + tr * 4;            // tile-local compacted row
    for (int u = 0; u < 4; ++u) {
        float2 o = make_float2((float)(acc[u][0] * (1.0 / 1024.0)),
                               (float)(acc[u][1] * (1.0 / 1024.0)));
        *(float2*)&simT[(size_t)(rbase + u) * N + col0 + tc * 2] = o;
    }
}

// Standalone gemm (tile 0 of each round).
__global__ __launch_bounds__(256) void k_gemm(const float* __restrict__ E,
                                              const int* __restrict__ idx,
                                              const int* __restrict__ nAp,
                                              float* __restrict__ simT,
                                              int t0, int bx0) {
    __shared__ double As[GBK][ASTR];
    __shared__ double Bs[GBK][BSTR];
    __shared__ int ra[64], ca[32];
    gemm_body(E, idx, *nAp, simT, t0, blockIdx.y, blockIdx.x + bx0, As, Bs, ra, ca);
}

// Exact per-row candidate list (compacted space): ballot-compact candidates
// {cc>cr, v>=thr, !mgC[cc]-at-tile-start}, bitonic-sort next_pow2(m) keys
// ((~v_bits)<<32)|cc ascending == (val desc, compacted idx asc) == original
// (val desc, idx asc). Output: u16 compacted ids, 128 sentinels after m.
__global__ __launch_bounds__(1024) void k_sort(const float* __restrict__ simT,
                                               const int* __restrict__ nAp,
                                               const uint8_t* __restrict__ mgC,
                                               int t0, uint16_t* __restrict__ lists) {
    int nA = *nAp;
    int r = blockIdx.x;
    int cr = t0 + r;
    int t = threadIdx.x;
    if (cr >= nA) return;                    // beyond live range: walk never reads
    __shared__ uint64_t key[4096];           // 32 KB
    __shared__ int cnt;
    uint16_t* out = lists + (size_t)r * LSTR;
    if (mgC[cr]) {                           // consumed earlier this round
        if (t < 128) out[t] = (uint16_t)0xFFFFu;
        return;
    }
    if (t == 0) cnt = 0;
    __syncthreads();
    const float* row = simT + (size_t)r * N;
    int lane = t & 63;
    for (int cc = cr + 1 + t; cc < nA; cc += 1024) {
        float v = row[cc];
        bool ok = (v >= THRF) && (!mgC[cc]); // NaN-safe: NaN fails v>=THRF
        unsigned long long mask = __ballot(ok);
        int wbase = 0;
        if (lane == 0 && mask) wbase = atomicAdd(&cnt, (int)__popcll(mask));
        wbase = __shfl(wbase, 0);
        if (ok) {
            int pos = wbase + (int)__popcll(mask & ((1ull << lane) - 1ull));
            uint32_t vb = __float_as_uint(v);    // v>0 => bit pattern monotone
            key[pos] = ((((uint64_t)(~vb)) << 32) | (uint32_t)cc);
        }
    }
    __syncthreads();
    int m = cnt;
    int sm = 1; while (sm < m) sm <<= 1;     // next pow2 (>=1)
    for (int x = m + t; x < sm; x += 1024) key[x] = ~0ull;   // pad sorts to end
    __syncthreads();
    for (int k = 2; k <= sm; k <<= 1) {
        for (int s = k >> 1; s > 0; s >>= 1) {
            for (int jj = t; jj < sm; jj += 1024) {
                int l = jj ^ s;
                if (l > jj) {
                    uint64_t a = key[jj], b = key[l];
                    bool asc = ((jj & k) == 0);
                    if ((a > b) == asc) { key[jj] = b; key[l] = a; }
                }
            }
            __syncthreads();
        }
    }
    for (int jj = t; jj < m; jj += 1024)
        out[jj] = (uint16_t)(key[jj] & 0xFFFFu);
    for (int x = m + t; x < m + 128; x += 1024) out[x] = (uint16_t)0xFFFFu;
}

// Rare slow path (R24-proven): row rr (half h) exhausted its 62 preloaded
// entries while full. Probes FRESH global chunks AFTER all prior commits
// (in-order DS -> stale-free).
__device__ __forceinline__ int refill_row(const uint16_t* __restrict__ lists,
                                          const uint8_t* msk, int h, int rr, int lane) {
    int half = lane >> 5, hl = lane & 31;
    int base = 62;
    while (base + 62 <= LSTR) {
        uint32_t d0 = 4096u, d1 = 4096u; bool w1 = false;
        if (half == h && hl < 31) {
            ushort2 g = *(const ushort2*)(lists + (size_t)rr * LSTR + base + 2 * hl);
            w1 = (g.y != 0xFFFFu);
            d0 = (g.x > 4095u) ? 4096u : (uint32_t)g.x;
            d1 = (g.y > 4095u) ? 4096u : (uint32_t)g.y;
        }
        bool b0 = (msk[d0] == 0), b1 = (msk[d1] == 0);
        uint32_t pk = b0 ? d0 : d1;
        unsigned long long rb = __ballot(b0 || b1);
        unsigned long long rv = __ballot(w1);
        uint32_t rm = (uint32_t)(rb >> (h * 32)) & 0x7FFFFFFFu;
        if (rm) return __builtin_amdgcn_readlane((int)pk, h * 32 + __builtin_ctz(rm));
        if (!((rv >> (h * 32 + 30)) & 1)) return -1;   // sentinel: exhausted
        base += 62;
    }
    return -1;
}

// One PAIR of rows (pr, pr+1) resolved per probe round-trip (R24-proven
// resolve), chunk register CH reloaded for pair+4 (R27-proven de-rotation).
#define PBODY(K, CH)                                                           \
    {                                                                          \
        int pr = pb + 2 * (K);                                                 \
        if (pr < nrows) {                                                      \
            int row1 = pr + 1;                                                 \
            if ((pr & 63) == 0)                                                \
                skiphint = __ballot(msk[t0w + pr + lane] != 0);                \
            bool sk0 = (skiphint >> (pr & 63)) & 1ull;                         \
            bool sk1 = (row1 < nrows) ? (((skiphint >> ((pr & 63) + 1)) & 1ull) != 0) : true; \
            if (sk0 && sk1) {                                                  \
                if (lane == 0) { pt[pr] = -1; if (row1 < nrows) pt[row1] = -1; } \
            } else {                                                           \
                uint32_t rc0, rc1; bool v1r = false;                           \
                int myrow = pr + half;                                         \
                if (hl == 31) {                                                \
                    rc0 = (myrow < nrows) ? (uint32_t)(t0w + myrow) : 4096u;   \
                    rc1 = 4096u;                                               \
                } else {                                                       \
                    uint32_t x0 = (CH) & 0xFFFFu, x1 = (CH) >> 16;             \
                    v1r = (x1 != 0xFFFFu);                                     \
                    rc0 = (x0 > 4095u) ? 4096u : x0;                           \
                    rc1 = (x1 > 4095u) ? 4096u : x1;                           \
                }                                                              \
                bool a0 = (msk[rc0] == 0);                                     \
                bool a1 = (msk[rc1] == 0);                                     \
                uint32_t pick = a0 ? rc0 : rc1;                                \
                unsigned long long balA = __ballot(a0);                        \
                unsigned long long balB = __ballot(a1);                        \
                unsigned long long bal = balA | balB;                          \
                unsigned long long vbal = __ballot(v1r);                       \
                uint32_t bl = (uint32_t)bal;                                   \
                uint32_t bh = (uint32_t)(bal >> 32);                           \
                bool full0 = (vbal >> 30) & 1ull;                              \
                bool full1 = (vbal >> 62) & 1ull;                              \
                int p1 = -1, p2 = -1;                                          \
                if (!sk0 && ((bl >> 31) & 1u)) {                               \
                    uint32_t m1 = bl & 0x7FFFFFFFu;                            \
                    if (m1) p1 = __builtin_amdgcn_readlane((int)pick, __builtin_ctz(m1)); \
                    else if (full0) p1 = refill_row(lists, msk, 0, pr, lane);  \
                }                                                              \
                if (lane == 0 && p1 >= 0) msk[p1] = 1;                         \
                bool alive1 = !sk1 && ((bh >> 31) & 1u) && (p1 != t0w + row1); \
                if (alive1) {                                                  \
                    uint32_t m2 = bh & 0x7FFFFFFFu;                            \
                    if (m2) {                                                  \
                        int f2 = __builtin_ctz(m2);                            \
                        p2 = __builtin_amdgcn_readlane((int)pick, 32 + f2);    \
                        if (p2 == p1) {                                        \
                            bool lA = (balA >> (32 + f2)) & 1ull;              \
                            bool lB = (balB >> (32 + f2)) & 1ull;              \
                            if (lA && lB) {                                    \
                                p2 = __builtin_amdgcn_readlane((int)rc1, 32 + f2); \
                            } else {                                           \
                                m2 &= ~(1u << f2);                             \
                                if (m2) p2 = __builtin_amdgcn_readlane((int)pick, 32 + __builtin_ctz(m2)); \
                                else if (full1) p2 = refill_row(lists, msk, 1, row1, lane); \
                                else p2 = -1;                                  \
                            }                                                  \
                        }                                                      \
                    } else if (full1) p2 = refill_row(lists, msk, 1, row1, lane); \
                }                                                              \
                if (lane == 0) {                                               \
                    if (p2 >= 0) msk[p2] = 1;                                  \
                    pt[pr] = (short)p1;                                        \
                    if (row1 < nrows) pt[row1] = (short)p2;                    \
                }                                                              \
                nm += (p1 >= 0) + (p2 >= 0);                                   \
            }                                                                  \
        }                                                                      \
        (CH) = 0xFFFFFFFFu;                                                    \
        { int nr = pb + 2 * (K) + 8 + half;                                    \
          if (nr < nrows && hl < 31)                                           \
              (CH) = *(const uint32_t*)(lists + (size_t)nr * LSTR + hl * 2); } \
    }

// Fused: block 0 = paired walk(tile t0w), blocks 1.. = gemm(tile t0g).
__global__ __launch_bounds__(256) void k_wgemm(const float* __restrict__ E,
                                               const int* __restrict__ idx,
                                               const int* __restrict__ nAp,
                                               float* __restrict__ simT,
                                               const uint16_t* __restrict__ lists,
                                               uint8_t* __restrict__ mgC,
                                               int* __restrict__ partner,
                                               uint8_t* __restrict__ consumedO,
                                               int t0w, int t0g, int bx0g,
                                               int* __restrict__ mcnt, int round) {
    __shared__ double As[GBK][ASTR];         // gemm blocks (~33 KB)
    __shared__ double Bs[GBK][BSTR];
    __shared__ int ra[64], ca[32];
    __shared__ __align__(8) uint8_t msk[N + 8];  // walk block (~5 KB)
    __shared__ short pt[TILE];
    int nA = *nAp;
    if (blockIdx.x != 0) {                   // ---- gemm tile t0g ----
        int b = blockIdx.x - 1;
        gemm_body(E, idx, nA, simT, t0g, b & 7, (b >> 3) + bx0g, As, Bs, ra, ca);
        return;
    }
    // ---- walk tile t0w: paired, 4-pair-deep named-register prefetch ----
    int nrows = nA - t0w; if (nrows > TILE) nrows = TILE;
    if (nrows <= 0) return;                  // uniform
    int tid = threadIdx.x;
    for (int x = tid; x < N / 8; x += 256)
        ((unsigned long long*)msk)[x] = ((const unsigned long long*)mgC)[x];
    if (tid == 0) *(unsigned long long*)(msk + N) = 0x0101010101010101ull;
    __syncthreads();
    if (tid >= 64) return;                   // waves 1-3 done; wave 0 never barriers
    int lane = tid;
    int half = lane >> 5, hl = lane & 31;
    int nm = 0;
    unsigned long long skiphint = 0ull;      // window-start consumed rows (monotone)
    uint32_t q0 = 0xFFFFFFFFu, q1 = 0xFFFFFFFFu, q2 = 0xFFFFFFFFu, q3 = 0xFFFFFFFFu;
    if (hl < 31) {                           // pairs 0..3 = rows 0..7
        if (half + 0 < nrows) q0 = *(const uint32_t*)(lists + (size_t)(half + 0) * LSTR + hl * 2);
        if (half + 2 < nrows) q1 = *(const uint32_t*)(lists + (size_t)(half + 2) * LSTR + hl * 2);
        if (half + 4 < nrows) q2 = *(const uint32_t*)(lists + (size_t)(half + 4) * LSTR + hl * 2);
        if (half + 6 < nrows) q3 = *(const uint32_t*)(lists + (size_t)(half + 6) * LSTR + hl * 2);
    }
    for (int pb = 0; pb < nrows; pb += 8) {
        PBODY(0, q0)
        PBODY(1, q1)
        PBODY(2, q2)
        PBODY(3, q3)
    }
    for (int r2 = lane; r2 < nrows; r2 += 64) {   // translate via global idx
        int p = pt[r2];
        int po = (p < 0) ? -1 : idx[p];
        partner[idx[t0w + r2]] = po;         // others stay -1 from k_prep
        if (po >= 0) consumedO[po] = 1;      // picks unique: no write races
    }
    for (int w = lane; w < N / 8; w += 64)   // mask writeback (beyond nA: ignored)
        ((unsigned long long*)mgC)[w] = ((const unsigned long long*)msk)[w];
    if (lane == 0 && nm) atomicAdd(&mcnt[round], nm);
}

// fuse + zero in one pass: block i owns E[i] AND its consumed partner E[p]
// (picks unique; consumed rows never fuse -> exclusive, race-free).
__global__ void k_fz(float* __restrict__ E, const int* __restrict__ partner) {
    int i = blockIdx.x;
    int p = partner[i];
    if (p < 0) return;
    float* ri = E + (size_t)i * D;
    float* rp = E + (size_t)p * D;
    for (int e = threadIdx.x; e < D; e += blockDim.x) {
        ri[e] = fminf(ri[e] + rp[e], 1.0f);
        rp[e] = 0.0f;
    }
}

// Final output: alive = round-3 alive minus round-3 consumption; acnt[4].
__global__ __launch_bounds__(256) void k_alive_out(const uint8_t* __restrict__ alive,
                                                   const uint8_t* __restrict__ consumedO,
                                                   float* __restrict__ outA,
                                                   int* __restrict__ acnt) {
    int x = blockIdx.x * 256 + threadIdx.x;
    int lane = threadIdx.x & 63;
    uint8_t na = (uint8_t)(alive[x] && !consumedO[x]);
    outA[x] = na ? 1.0f : 0.0f;
    unsigned long long b = __ballot(na != 0);
    if (lane == 0) atomicAdd(&acnt[4], (int)__popcll(b));
}

// AUDIT: fires ONLY on invariant violation (after+m==before, 2m<=before).
__global__ void k_diag(const int* __restrict__ mcnt, const int* __restrict__ acnt,
                       float* __restrict__ out) {
    bool bad = false;
    for (int r = 0; r < 4; ++r) {
        int before = acnt[r], after = acnt[r + 1], m = mcnt[r];
        if (after + m != before) bad = true;
        if (2 * m > before) bad = true;
        if (m < 0 || m > 2048) bad = true;
    }
    if (bad) out[0] = (float)(8.0e6 + (double)mcnt[0] * 2048.0 + (double)mcnt[1]);
}

extern "C" void kernel_launch(void* const* d_in, const int* in_sizes, int n_in,
                              void* d_out, int out_size, void* d_ws, size_t ws_size,
                              hipStream_t stream) {
    const float* Ein = (const float*)d_in[0];
    float* E = (float*)d_out;                    // 4096*1024 fp32, updated in place
    float* outAlive = E + (size_t)N * D;         // 4096 floats (0/1)

    // arena = d_in[0] after the on-stream copy below (16 MB guaranteed)
    char* ws = (char*)d_in[0];
    float* simT = (float*)ws;        ws += (size_t)TILE * N * 4;      // 8 MB
    uint16_t* lists = (uint16_t*)ws; ws += (size_t)TILE * LSTR * 2;   // 4.125 MB
    int* partner = (int*)ws;         ws += (size_t)N * 4;             // 16 KB
    int* idx = (int*)ws;             ws += (size_t)N * 4;             // 16 KB
    int* mcnt = (int*)ws;            ws += 8 * 4;
    int* acnt = (int*)ws;            ws += 8 * 4;
    int* nA = (int*)ws;              ws += 16;   // padded for alignment below
    uint8_t* mgC = (uint8_t*)ws;     ws += N;
    uint8_t* alive = (uint8_t*)ws;   ws += N;
    uint8_t* consumedO = (uint8_t*)ws;           // total ~12.4 MB << 16 MB

    hipMemcpyAsync(E, Ein, (size_t)N * D * sizeof(float), hipMemcpyDeviceToDevice, stream);
    k_init<<<(N + 255) / 256, 256, 0, stream>>>(alive, consumedO, mcnt, acnt);

    for (int round = 0; round < 4; ++round) {
        k_prep<<<1, 1024, 0, stream>>>(alive, consumedO, idx, nA, mgC, partner,
                                       acnt, round);
        k_gemm<<<dim3(128, 8), 256, 0, stream>>>(E, idx, nA, simT, 0, 0);
        for (int t = 0; t < 8; ++t) {
            int t0 = t * TILE;
            k_sort<<<TILE, 1024, 0, stream>>>(simT, nA, mgC, t0, lists);
            int tg = t + 1;
            int bx0g = tg * 16;               // tile tg cols start at block tg*512/32
            int gb = (tg < 8) ? (128 - bx0g) * 8 : 0;
            k_wgemm<<<1 + gb, 256, 0, stream>>>(E, idx, nA, simT, lists, mgC,
                                                partner, consumedO, t0, tg * TILE,
                                                bx0g, mcnt, round);
        }
        k_fz<<<N, 256, 0, stream>>>(E, partner);
    }
    k_alive_out<<<16, 256, 0, stream>>>(alive, consumedO, outAlive, acnt);
    k_diag<<<1, 1, 0, stream>>>(mcnt, acnt, E);   // conditional sentinel only
}